// Round 6
// baseline (91.369 us; speedup 1.0000x reference)
//
#include <hip/hip_runtime.h>

// SlidingKernelAttention: unfold(k=4,s=1) -> per-(b,c,patch-offset) attention
// over seq=256 tokens of dim=16 -> overlap-add fold.
// B=2, C=64, H=W=67, Ho=Wo=64, N = B*C*16 = 2048 independent sequences.
//
// R15 = R14 resubmitted (R14's bench died in the harness: "container failed
// twice" — infra, no counters). One safety change: R14's cross-seq x
// prefetch used float4 casts at 4B-aligned addresses (xb + roff + sq,
// sq=1..3) — source-level UB and the only new fault candidate. Now 4
// scalar float loads (issue as one clause; same latency hiding).
//
// Theory (R12-R13 evidence): pass1(36us) = M(11us main loop, trans-pipe
// floor) + P(25us REP-independent). P ignored instruction deletion (R13),
// occupancy knobs (R9-R11) -> P is latency EXPOSURE of each block's serial
// prologue (x VMEM -> projection -> barrier). Fix: block serially owns the
// 4 sequences (bc, oi, oj=0..3) whose x windows differ by a 1-column
// shift; seq i+1's x loads issue after seq i's projection, consumed after
// seq i's ~1.4us main loop -> 3 of 4 prologue exposures hidden, 4x fewer
// block ramps. KV double-buffered (2x16KB halves, buf[sq&1]); one barrier
// per seq (half reused at sq+2 is protected by the sq+1 barrier). Grid
// 512 = 8 XCDs x 64 (bc [16k,16k+16) on XCD k, matching pass2), 2
// blocks/CU, launch_bounds(512,2). Main loop & epilogue unchanged from
// R11/R13 (M is at the trans floor).
//
// MFMA layout identity (R5-R8): 16x16 MFMA C/D layout == A-operand layout
// == B-operand layout, so projection MFMA results ARE attention operands:
//   K^T = Wk.X^T    -> A-frag of K      (for S^T = K.Q^T)
//   V   = X.Wv^T    -> A-frag of V^T    (for O^T = V^T.P^T)
//   Q^T = s.Wq.X^T  -> B-frag of Q^T
//   P^T = exp2(S^T) -> B-frag of P^T    (in-register)
// All fragments statically indexed (R4 lesson: dynamic reg-array indexing
// -> scratch lowering). f16 vectors built via v_cvt_pkrtz + bit_cast /
// shufflevector only (R8: no sub-register insert/extract).
// Timed window includes a ~43-50us harness fill of the 268MB d_ws
// (read deltas as total minus the per-run fill dur from the counters).

#define BATCH 2
#define CHAN 64
#define HWDIM 67
#define SEQ 256
#define DIM 16
#define NSEQ 2048            // BATCH*CHAN*16
#define PLANE 4096           // 64*64 elems per sequence
#define OUT_TOTAL (BATCH * CHAN * HWDIM * HWDIM)   // 574592
#define ATT_SCALE 0.70710678118654752f             // (DIM/HEADS)^-0.5
#define LOG2E 1.44269504088896340736f
#define HTILES 17            // ceil(67/4) output-row tiles per bc

typedef _Float16 half4 __attribute__((ext_vector_type(4)));
typedef _Float16 half8 __attribute__((ext_vector_type(8)));
typedef float float4v __attribute__((ext_vector_type(4)));
typedef __fp16 fp16x2 __attribute__((ext_vector_type(2)));
typedef unsigned int uint2v __attribute__((ext_vector_type(2)));

// 2x v_cvt_pkrtz + register-pair aliasing: zero insert/extract VALU.
static __device__ __forceinline__ half4 mk_half4(float a, float b, float c, float d) {
    fp16x2 lo = __builtin_amdgcn_cvt_pkrtz(a, b);
    fp16x2 hi = __builtin_amdgcn_cvt_pkrtz(c, d);
    uint2v u;
    u[0] = __builtin_bit_cast(unsigned int, lo);
    u[1] = __builtin_bit_cast(unsigned int, hi);
    return __builtin_bit_cast(half4, u);
}

static __device__ __forceinline__ half4 pack4(float4v c) {
    return mk_half4(c[0], c[1], c[2], c[3]);
}

// one q-tile step: exp2 the 4 scores, accumulate denominator, pack,
// accumulate O^T.
static __device__ __forceinline__ void att_step(const half4 vf, const float4v sfr,
                                                float& l, float4v& oacc) {
    const float p0 = __builtin_amdgcn_exp2f(sfr[0]);
    const float p1 = __builtin_amdgcn_exp2f(sfr[1]);
    const float p2 = __builtin_amdgcn_exp2f(sfr[2]);
    const float p3 = __builtin_amdgcn_exp2f(sfr[3]);
    l += (p0 + p1) + (p2 + p3);
    const half4 pb = mk_half4(p0, p1, p2, p3);
    oacc = __builtin_amdgcn_mfma_f32_16x16x16f16(vf, pb, oacc, 0, 0, 0);
}

__global__ __launch_bounds__(512, 2) void ska_attn_pass1(
    const float* __restrict__ x,      // [B, C, 67, 67]
    const float* __restrict__ w,      // [48, 16]
    _Float16* __restrict__ ao)        // [NSEQ, 64, 64] workspace (f16)
{
    // double-buffered KV halves: buf[sq&1][t] holds tile t's fragments for
    // sequence sq: [0:4]=K A-frag | [4:8]=V^T A-frag. 2 x 16 KB.
    __shared__ __align__(16) _Float16 buf[2][16][64][8];

    // XCD chunked swizzle: 512 blocks = 8 XCDs x 64 -> bc [16k,16k+16) on
    // XCD k (matches pass2). Block b owns sequences (bc, oi, oj=0..3).
    const int b  = (int)(blockIdx.x & 7) * 64 + (int)(blockIdx.x >> 3);
    const int bc = b >> 2;
    const int oi = b & 3;
    const int n0 = bc * 16 + oi * 4;        // + sq, sq = oj = 0..3

    const int tid  = threadIdx.x;
    const int wave = tid >> 6;    // 0..7: owns q/k tiles 2w, 2w+1
    const int lane = tid & 63;
    const int o = lane & 15;      // token (and weight output row) for this lane
    const int g = lane >> 4;      // feature group (k-group)

    // weight fragments straight from global (3 KB, L1-resident)
    const float4 wq4 = *(const float4*)(w + ( 0 + o) * DIM + 4 * g);
    const float4 wk4 = *(const float4*)(w + (16 + o) * DIM + 4 * g);
    const float4 wv4 = *(const float4*)(w + (32 + o) * DIM + 4 * g);
    const half4 wqf = mk_half4(wq4.x * (ATT_SCALE * LOG2E), wq4.y * (ATT_SCALE * LOG2E),
                               wq4.z * (ATT_SCALE * LOG2E), wq4.w * (ATT_SCALE * LOG2E));
    const half4 wkf = mk_half4(wk4.x, wk4.y, wk4.z, wk4.w);
    const half4 wvf = mk_half4(wv4.x, wv4.y, wv4.z, wv4.w);

    const float4v zf = (float4v){0.f, 0.f, 0.f, 0.f};

    // X addressing (direct-to-register, R13): lane (o,g) of tile t holds
    // features 4g..4g+3 of token s=t*16+o, i.e.
    //   x[bc][oi + 4t + (o>>2)][ (o&3)*16 + 4g + oj ],  oj = sq.
    // Wave w owns tiles 2w, 2w+1 -> row offsets roff0/roff1.
    const float* xb = x + ((size_t)bc * HWDIM + oi) * HWDIM + (o & 3) * 16 + 4 * g;
    const int roff0 = (8 * wave + (o >> 2)) * HWDIM;
    const int roff1 = roff0 + 4 * HWDIM;

    // prologue prefetch for sq=0 (scalar loads: sq>0 addresses are only
    // 4B-aligned, so no float4 casts here)
    float xr0a = xb[roff0 + 0], xr0b = xb[roff0 + 1],
          xr0c = xb[roff0 + 2], xr0d = xb[roff0 + 3];
    float xr1a = xb[roff1 + 0], xr1b = xb[roff1 + 1],
          xr1c = xb[roff1 + 2], xr1d = xb[roff1 + 3];

    for (int sq = 0; sq < 4; ++sq) {
        const int cur = sq & 1;

        // projection for seq sq from the prefetched x registers
        half4 qfr0, qfr1;
        {
            const half4 xf0 = mk_half4(xr0a, xr0b, xr0c, xr0d);
            const half4 kf0 = pack4(__builtin_amdgcn_mfma_f32_16x16x16f16(wkf, xf0, zf, 0, 0, 0));
            const half4 vf0 = pack4(__builtin_amdgcn_mfma_f32_16x16x16f16(xf0, wvf, zf, 0, 0, 0));
            *(half8*)&buf[cur][2 * wave][lane][0] =
                __builtin_shufflevector(kf0, vf0, 0, 1, 2, 3, 4, 5, 6, 7);
            qfr0 = pack4(__builtin_amdgcn_mfma_f32_16x16x16f16(wqf, xf0, zf, 0, 0, 0));

            const half4 xf1 = mk_half4(xr1a, xr1b, xr1c, xr1d);
            const half4 kf1 = pack4(__builtin_amdgcn_mfma_f32_16x16x16f16(wkf, xf1, zf, 0, 0, 0));
            const half4 vf1 = pack4(__builtin_amdgcn_mfma_f32_16x16x16f16(xf1, wvf, zf, 0, 0, 0));
            *(half8*)&buf[cur][2 * wave + 1][lane][0] =
                __builtin_shufflevector(kf1, vf1, 0, 1, 2, 3, 4, 5, 6, 7);
            qfr1 = pack4(__builtin_amdgcn_mfma_f32_16x16x16f16(wqf, xf1, zf, 0, 0, 0));
        }

        // issue next sequence's x loads now; consumed after this main loop
        // (oj shift of +1 column -> L1/L2-resident). Latency hides under
        // the ~1.4us main loop below.
        if (sq < 3) {
            const int d = sq + 1;
            xr0a = xb[roff0 + d + 0]; xr0b = xb[roff0 + d + 1];
            xr0c = xb[roff0 + d + 2]; xr0d = xb[roff0 + d + 3];
            xr1a = xb[roff1 + d + 0]; xr1b = xb[roff1 + d + 1];
            xr1c = xb[roff1 + d + 2]; xr1d = xb[roff1 + d + 3];
        }

        __syncthreads();   // kv frags of seq sq ready (one barrier per seq)

        float4v oacc0 = zf, oacc1 = zf;
        float l0 = 0.f, l1 = 0.f;

        // main loop: one ds_read_b128 per k-tile, prefetched one tile
        // ahead; 2 S-MFMAs issue before the exp2/pack/O-MFMA phase.
        half8 kvc = *(const half8*)&buf[cur][0][lane][0];
#pragma unroll 4
        for (int t = 0; t < 16; ++t) {
            const half8 kvn = *(const half8*)&buf[cur][(t + 1) & 15][lane][0];
            const half4 kf = __builtin_shufflevector(kvc, kvc, 0, 1, 2, 3);
            const half4 vf = __builtin_shufflevector(kvc, kvc, 4, 5, 6, 7);
            const float4v s0 = __builtin_amdgcn_mfma_f32_16x16x16f16(kf, qfr0, zf, 0, 0, 0);
            const float4v s1 = __builtin_amdgcn_mfma_f32_16x16x16f16(kf, qfr1, zf, 0, 0, 0);
            att_step(vf, s0, l0, oacc0);
            att_step(vf, s1, l1, oacc1);
            kvc = kvn;
        }

        // softmax denom + store O^T frag for seq sq
        const int n = n0 + sq;
#pragma unroll
        for (int j = 0; j < 2; ++j) {
            float lj = j ? l1 : l0;
            lj += __shfl_xor(lj, 16, 64);
            lj += __shfl_xor(lj, 32, 64);
            const float rl = __builtin_amdgcn_rcpf(lj);
            const float4v oa = j ? oacc1 : oacc0;
            const int query = (2 * wave + j) * 16 + o;
            const half4 hv = mk_half4(oa[0] * rl, oa[1] * rl,
                                      oa[2] * rl, oa[3] * rl);
            *(half4*)(ao + (size_t)n * PLANE + query * DIM + 4 * g) = hv;
        }
        // no barrier here: next projection writes buf[(sq+1)&1]; reuse of
        // buf[sq&1] happens only after the NEXT barrier (hazard-free).
    }
}

// pass 2: block = (bc, 4 output rows). Stage the 16 planes x 4 rows of ao
// this block needs (8 KB) with coalesced 16B loads, then each pixel sums 16
// LDS halves. sA[pl][hh] holds ao[bc*16+pl][h0+hh - (pl>>2)][0:64] (0 if OOB).
__global__ __launch_bounds__(256) void ska_fold_pass2(
    const _Float16* __restrict__ ao,  // [NSEQ, 64, 64] f16
    float* __restrict__ out)          // [B, C, 67, 67]
{
    __shared__ __align__(16) _Float16 sA[16][4][64];   // 8 KB

    // XCD chunked swizzle: 2176 blocks = 8 XCDs x 272 = 8 x (16 bc x 17
    // tiles). XCD k folds bc [16k,16k+16) — exactly the bc's whose ao was
    // written by pass1 on XCD k, so the staging reads hit warm L2.
    const int blk = (int)(blockIdx.x & 7) * 272 + (int)(blockIdx.x >> 3);
    const int h0  = (blk % HTILES) * 4;
    const int bc  = blk / HTILES;
    const int tid = threadIdx.x;

    // stage: 4096 halves, 16 per thread as 2x half8
    {
        const int pl = tid >> 4;           // plane 0..15
        const int hh = (tid >> 2) & 3;     // local row 0..3
        const int pw = (tid & 3) * 16;     // col base 0/16/32/48
        const int i  = pl >> 2;
        const int prow = h0 + hh - i;      // source plane row
        half8 v0, v1;
        if (prow >= 0 && prow < 64) {
            const _Float16* src = ao + ((size_t)(bc * 16 + pl)) * PLANE + prow * 64 + pw;
            v0 = *(const half8*)src;
            v1 = *(const half8*)(src + 8);
        } else {
            const half8 z = (half8)(_Float16)0.f;
            v0 = z; v1 = z;
        }
        *(half8*)&sA[pl][hh][pw]     = v0;
        *(half8*)&sA[pl][hh][pw + 8] = v1;
    }
    __syncthreads();

    for (int px = tid; px < 4 * HWDIM; px += 256) {
        const int hh = px / HWDIM;
        const int ww = px % HWDIM;
        const int h  = h0 + hh;
        if (h >= HWDIM) continue;
        float acc = 0.f;
#pragma unroll
        for (int i = 0; i < 4; ++i) {
#pragma unroll
            for (int j = 0; j < 4; ++j) {
                const int pw = ww - j;
                if (pw < 0 || pw >= 64) continue;
                acc += (float)sA[i * 4 + j][hh][pw];
            }
        }
        out[((size_t)bc * HWDIM + h) * HWDIM + ww] = acc;
    }
}

// ---- fallback (atomic fold) if workspace is too small ----
__global__ __launch_bounds__(256) void ska_attn_atomic(
    const float* __restrict__ x, const float* __restrict__ w,
    float* __restrict__ out)
{
    __shared__ float sw[3 * DIM * DIM];
    __shared__ float sk[SEQ][DIM];
    __shared__ float sv[SEQ][DIM];

    const int n = blockIdx.x, p = n & 15, bc = n >> 4, oi = p >> 2, oj = p & 3;
    const int s = threadIdx.x, ph = s >> 2, pw0 = (s & 3) * DIM;

#pragma unroll
    for (int r = 0; r < 3; ++r) sw[r * 256 + s] = w[r * 256 + s];

    const float* xrow = x + ((size_t)bc * HWDIM + (ph + oi)) * HWDIM + pw0 + oj;
    float xr[DIM];
#pragma unroll
    for (int d = 0; d < DIM; ++d) xr[d] = xrow[d];
    __syncthreads();

    float q[DIM];
#pragma unroll
    for (int o = 0; o < DIM; ++o) {
        float aq = 0.f, ak = 0.f, av = 0.f;
#pragma unroll
        for (int d = 0; d < DIM; ++d) {
            aq += xr[d] * sw[o * DIM + d];
            ak += xr[d] * sw[(DIM + o) * DIM + d];
            av += xr[d] * sw[(2 * DIM + o) * DIM + d];
        }
        q[o] = aq * ATT_SCALE; sk[s][o] = ak; sv[s][o] = av;
    }
    __syncthreads();

    float l = 0.f, acc[DIM];
#pragma unroll
    for (int d = 0; d < DIM; ++d) acc[d] = 0.f;
    for (int t = 0; t < SEQ; ++t) {
        float sc = 0.f;
#pragma unroll
        for (int d = 0; d < DIM; ++d) sc += q[d] * sk[t][d];
        const float pe = __expf(sc);
        l += pe;
#pragma unroll
        for (int d = 0; d < DIM; ++d) acc[d] += pe * sv[t][d];
    }
    const float rl = 1.f / l;
    float* obase = out + ((size_t)bc * HWDIM + (ph + oi)) * HWDIM + pw0 + oj;
#pragma unroll
    for (int d = 0; d < DIM; ++d) atomicAdd(&obase[d], acc[d] * rl);
}

extern "C" void kernel_launch(void* const* d_in, const int* in_sizes, int n_in,
                              void* d_out, int out_size, void* d_ws, size_t ws_size,
                              hipStream_t stream) {
    const float* x = (const float*)d_in[0];
    const float* w = (const float*)d_in[1];
    float* out = (float*)d_out;

    const size_t need = (size_t)NSEQ * PLANE * sizeof(_Float16);   // 16.8 MB
    if (ws_size >= need) {
        _Float16* ao = (_Float16*)d_ws;
        ska_attn_pass1<<<NSEQ / 4, 512, 0, stream>>>(x, w, ao);
        ska_fold_pass2<<<BATCH * CHAN * HTILES, 256, 0, stream>>>(ao, out);
    } else {
        (void)hipMemsetAsync(out, 0, (size_t)out_size * sizeof(float), stream);
        ska_attn_atomic<<<NSEQ, 256, 0, stream>>>(x, w, out);
    }
}